// Round 10
// baseline (149.514 us; speedup 1.0000x reference)
//
#include <hip/hip_runtime.h>
#include <math.h>

#define B_    2
#define N_    2048
#define DIM_  1024
#define H_    16
#define D_    64
#define INNER_ 1024
#define QKVC_ 3072

typedef __attribute__((ext_vector_type(8))) short short8;
typedef __attribute__((ext_vector_type(4))) short short4v;
typedef __attribute__((ext_vector_type(4))) float f32x4;
typedef __attribute__((ext_vector_type(4))) float float4v;
typedef _Float16 half8 __attribute__((ext_vector_type(8)));
typedef __fp16 fp16v2 __attribute__((ext_vector_type(2)));

union h8u { short8 s; half8 h; fp16v2 h2[4]; };
static __device__ __forceinline__ half8 s2h(short8 s) { h8u u; u.s = s; return u.h; }

static __device__ __forceinline__ unsigned short f2h(float f) {
    _Float16 h = (_Float16)f;
    unsigned short u;
    __builtin_memcpy(&u, &h, 2);
    return u;
}
static __device__ __forceinline__ float h2f(unsigned short u) {
    _Float16 h;
    __builtin_memcpy(&h, &u, 2);
    return (float)h;
}

static __device__ __forceinline__ void gload16(const void* g, void* l) {
    __builtin_amdgcn_global_load_lds((__attribute__((address_space(1))) void*)(g),
                                     (__attribute__((address_space(3))) void*)(l),
                                     16, 0, 0);
}

// ---------------------------------------------------------------------------
// convert_x: fp32 (4096 x 1024) -> fp16, same layout. 8 elems/thread.
// ---------------------------------------------------------------------------
__global__ __launch_bounds__(256) void convert_x(const float* __restrict__ X,
                                                 unsigned short* __restrict__ Xh) {
    int t = blockIdx.x * blockDim.x + threadIdx.x;
    size_t off = (size_t)t * 8;
    float4v a = *(const float4v*)(X + off);
    float4v b = *(const float4v*)(X + off + 4);
    short8 o;
#pragma unroll
    for (int j = 0; j < 4; ++j) {
        o[j]     = (short)f2h(a[j]);
        o[4 + j] = (short)f2h(b[j]);
    }
    *(short8*)(Xh + off) = o;
}

// ---------------------------------------------------------------------------
// convert_w_T: W fp32 (K=1024 x Nw) -> W^T fp16 (Nw x 1024).
// ---------------------------------------------------------------------------
__global__ __launch_bounds__(256) void convert_w_T(const float* __restrict__ W,
                                                   unsigned short* __restrict__ Th,
                                                   int Nw) {
    __shared__ unsigned short Sh[64][65];
    const int tid = threadIdx.x;
    const int n0 = blockIdx.x * 64;
    const int k0 = blockIdx.y * 64;
#pragma unroll
    for (int l = 0; l < 16; ++l) {
        int idx = tid + l * 256;
        int r = idx >> 6, c = idx & 63;
        Sh[c][r] = f2h(W[(size_t)(k0 + r) * Nw + n0 + c]);
    }
    __syncthreads();
#pragma unroll
    for (int l = 0; l < 16; ++l) {
        int idx = tid + l * 256;
        int r = idx >> 6, c = idx & 63;
        Th[(size_t)(n0 + r) * 1024 + k0 + c] = Sh[r][c];
    }
}

// ---------------------------------------------------------------------------
// fp16 GEMM core: C(M x N) = A(M x 1024) * B^T(N x 1024), fp32 acc.
// ---------------------------------------------------------------------------
#define GEMM_STAGE_H(gA, gB)                                                       \
    {                                                                              \
        int rr0 = w * 32 + (lane >> 2), rr1 = w * 32 + 16 + (lane >> 2);           \
        int kc = (lane & 3) * 8;                                                   \
        gload16(gA + (size_t)(m0 + rr0) * 1024 + k0 + kc, sA + (w * 32) * 32);     \
        gload16(gA + (size_t)(m0 + rr1) * 1024 + k0 + kc, sA + (w * 32 + 16) * 32);\
        gload16(gB + (size_t)(n0 + rr0) * 1024 + k0 + kc, sB + (w * 32) * 32);     \
        gload16(gB + (size_t)(n0 + rr1) * 1024 + k0 + kc, sB + (w * 32 + 16) * 32);\
    }

#define GEMM_BODY_H()                                                              \
    half8 af[4], bf[4];                                                            \
    _Pragma("unroll") for (int f = 0; f < 4; ++f) {                                \
        af[f] = s2h(*(const short8*)&sA[(wr + f * 16 + (lane & 15)) * 32 + (lane >> 4) * 8]); \
        bf[f] = s2h(*(const short8*)&sB[(wc + f * 16 + (lane & 15)) * 32 + (lane >> 4) * 8]); \
    }                                                                              \
    _Pragma("unroll") for (int i = 0; i < 4; ++i)                                  \
        _Pragma("unroll") for (int j = 0; j < 4; ++j)                              \
            acc[i][j] = __builtin_amdgcn_mfma_f32_16x16x32_f16(af[i], bf[j], acc[i][j], 0, 0, 0);

__global__ __launch_bounds__(256) void qkv_gemm_mfma(const unsigned short* __restrict__ Ah,
                                                     const unsigned short* __restrict__ Bh,
                                                     unsigned short* __restrict__ Qh,
                                                     unsigned short* __restrict__ Kh,
                                                     unsigned short* __restrict__ Vh) {
    __shared__ __align__(16) unsigned short sA[4096], sB[4096];
    const int tid = threadIdx.x;
    const int lane = tid & 63, w = tid >> 6;
    const int wr = (w >> 1) * 64, wc = (w & 1) * 64;
    const int m0 = blockIdx.y * 128, n0 = blockIdx.x * 128;
    f32x4 acc[4][4] = {};

    for (int k0 = 0; k0 < 1024; k0 += 32) {
        GEMM_STAGE_H(Ah, Bh);
        __syncthreads();
        GEMM_BODY_H();
        __syncthreads();
    }

#pragma unroll
    for (int i = 0; i < 4; ++i) {
        int mbase = m0 + wr + i * 16 + (lane >> 4) * 4;
#pragma unroll
        for (int j = 0; j < 4; ++j) {
            int col = n0 + wc + j * 16 + (lane & 15);
            int seg = col >> 10;
            int wcol = col & 1023;
            int h = wcol >> 6, dd = wcol & 63;
            unsigned short* dst = (seg == 0) ? Qh : (seg == 1 ? Kh : Vh);
#pragma unroll
            for (int r = 0; r < 4; ++r) {
                int row = mbase + r;
                int b = row >> 11, n = row & (N_ - 1);
                dst[((size_t)(b * H_ + h) * N_ + n) * D_ + dd] = f2h(acc[i][j][r]);
            }
        }
    }
}

__global__ __launch_bounds__(256) void out_gemm_mfma(const unsigned short* __restrict__ Ah,
                                                     const unsigned short* __restrict__ Bh,
                                                     const float* __restrict__ bias,
                                                     float* __restrict__ C) {
    __shared__ __align__(16) unsigned short sA[4096], sB[4096];
    const int tid = threadIdx.x;
    const int lane = tid & 63, w = tid >> 6;
    const int wr = (w >> 1) * 64, wc = (w & 1) * 64;
    const int m0 = blockIdx.y * 128, n0 = blockIdx.x * 128;
    f32x4 acc[4][4] = {};

    for (int k0 = 0; k0 < 1024; k0 += 32) {
        GEMM_STAGE_H(Ah, Bh);
        __syncthreads();
        GEMM_BODY_H();
        __syncthreads();
    }

#pragma unroll
    for (int i = 0; i < 4; ++i) {
        int mbase = m0 + wr + i * 16 + (lane >> 4) * 4;
#pragma unroll
        for (int j = 0; j < 4; ++j) {
            int col = n0 + wc + j * 16 + (lane & 15);
            float bv = bias[col];
#pragma unroll
            for (int r = 0; r < 4; ++r)
                C[(size_t)(mbase + r) * DIM_ + col] = acc[i][j][r] + bv;
        }
    }
}

// ---------------------------------------------------------------------------
// RoPE in-place on fp16 Q and K. Q pre-scaled by 0.125*log2(e).
// ---------------------------------------------------------------------------
#define QSCALE 0.180336879963f   // 0.125 * log2(e)
__global__ void rope_kernel(unsigned short* __restrict__ Qh,
                            unsigned short* __restrict__ Kh) {
    const int total = B_ * H_ * N_ * (D_ / 2);
    for (int p = blockIdx.x * blockDim.x + threadIdx.x; p < total;
         p += gridDim.x * blockDim.x) {
        int d2 = p & 31;
        int rest = p >> 5;
        int n = rest & (N_ - 1);
        size_t off = (size_t)rest * D_ + 2 * d2;
        float freq = __builtin_amdgcn_exp2f((float)d2 * -0.4152410118f);
        float ang = (float)n * freq;
        float s, c;
        sincosf(ang, &s, &c);

        unsigned int uq = *(unsigned int*)(Qh + off);
        float q0 = h2f((unsigned short)(uq & 0xffff));
        float q1 = h2f((unsigned short)(uq >> 16));
        *(unsigned int*)(Qh + off) =
            (unsigned int)f2h((q0 * c - q1 * s) * QSCALE) |
            ((unsigned int)f2h((q1 * c + q0 * s) * QSCALE) << 16);

        unsigned int uk = *(unsigned int*)(Kh + off);
        float k0 = h2f((unsigned short)(uk & 0xffff));
        float k1 = h2f((unsigned short)(uk >> 16));
        *(unsigned int*)(Kh + off) = (unsigned int)f2h(k0 * c - k1 * s) |
                                     ((unsigned int)f2h(k1 * c + k0 * s) << 16);
    }
}

// ---------------------------------------------------------------------------
// Flash attention v5: 4 waves x 32 q-rows (2 q-subtiles/wave). K LDS dbuf
// (gload_lds, XOR-swz); V LDS dbuf in PERMUTED transpose layout:
//   Vt[d][kv'], kv' = (kv>>5)*32 + ((kv>>2)&3)*8 + ((kv>>4)&1)*4 + (kv&3)
// so each PV B-frag is ONE ds_read_b128 (col groups XOR-swz by d&7).
// K and V fragments are q-independent -> reused across both q-subs.
// ---------------------------------------------------------------------------
#define NT   (N_ / 64)
#define RESC_THR 8.0f
__global__ __launch_bounds__(256, 2) void attn_mfma(const unsigned short* __restrict__ Qh,
                                                    const unsigned short* __restrict__ Kh,
                                                    const unsigned short* __restrict__ Vh,
                                                    unsigned short* __restrict__ Oh) {
    __shared__ __align__(16) unsigned short Ks[2 * 64 * 64];   // K rows, XOR-swz 8-grps
    __shared__ __align__(16) unsigned short Vt[2][64][64];     // permuted V^T
    const int tid = threadIdx.x;
    const int w = tid >> 6;
    const int l = tid & 63;
    const int lr = l & 15, lg = l >> 4;

    // XCD remap: xcd x owns bh in [4x, 4x+4)
    const int f = blockIdx.y * gridDim.x + blockIdx.x;          // 0..511
    const int x = f & 7, g = f >> 3;
    const int bh = x * 4 + (g >> 4);
    const int q0 = (g & 15) * 128;
    const size_t base = (size_t)bh * N_ * D_;

    // K staging: thread stages rows srow and srow+32 (same XOR group)
    const int srow = tid >> 3;            // 0..31
    const int scg  = tid & 7;
    const int gcg  = scg ^ (srow & 7);
    const unsigned short* ksrc = Kh + base + (size_t)srow * D_ + gcg * 8;
    unsigned short* kdst = Ks + w * 512;  // wave-uniform; HW adds lane*16B

    // V staging: thread loads V[kv0..kv0+3][d0..d0+3]
    const int kv0 = (tid >> 4) * 4;       // 0..60
    const int d0  = (tid & 15) * 4;
    // kv' base for the 4-row group (r = 0..3 consecutive in kv')
    const int kvp = ((kv0 >> 5) * 32) + (((kv0 >> 2) & 3) * 8) + (((kv0 >> 4) & 1) * 4);
    const int kvpg = kvp >> 3, kvpo = kvp & 7;

    // Q fragments, 2 subs: rows q0 + w*32 + s*16 + lr
    half8 qf[2][2];
#pragma unroll
    for (int s = 0; s < 2; ++s) {
        const unsigned short* qrow = Qh + base + (size_t)(q0 + w * 32 + s * 16 + lr) * D_ + lg * 8;
        qf[s][0] = s2h(*(const short8*)qrow);
        qf[s][1] = s2h(*(const short8*)(qrow + 32));
    }

    f32x4 oacc[2][4] = {};              // [sub][dt]: q=lg*4+r, d=dt*16+lr
    float mrow[2] = {-1e30f, -1e30f}, lsum[2] = {0.f, 0.f};

    // ---- prologue: stage tile 0 into buffer 0 ----
    gload16(ksrc, kdst);
    gload16(ksrc + 32 * D_, kdst + 2048);
    {
        short4v ld[4];
#pragma unroll
        for (int i = 0; i < 4; ++i)
            ld[i] = *(const short4v*)(Vh + base + (size_t)(kv0 + i) * D_ + d0);
#pragma unroll
        for (int j = 0; j < 4; ++j) {
            int d = d0 + j;
            short4v t4 = {ld[0][j], ld[1][j], ld[2][j], ld[3][j]};
            *(short4v*)&Vt[0][d][((kvpg ^ (d & 7)) << 3) + kvpo] = t4;
        }
    }

    for (int ti = 0; ti < NT; ++ti) {
        const int cur = ti & 1, nxt = cur ^ 1;
        __syncthreads();

        // ---- issue tile ti+1 staging early ----
        short4v ld[4] = {};
        if (ti + 1 < NT) {
            gload16(ksrc + (size_t)(ti + 1) * 64 * D_, kdst + nxt * 4096);
            gload16(ksrc + (size_t)((ti + 1) * 64 + 32) * D_, kdst + nxt * 4096 + 2048);
#pragma unroll
            for (int i = 0; i < 4; ++i)
                ld[i] = *(const short4v*)(Vh + base + (size_t)((ti + 1) * 64 + kv0 + i) * D_ + d0);
        }

        // ---- K fragments (shared by both q-subs): 8 ds_read_b128 ----
        half8 kf[8];
#pragma unroll
        for (int t = 0; t < 4; ++t) {
            int row = t * 16 + lr;
            int swz = row & 7;
            const unsigned short* kr = Ks + cur * 4096 + row * 64;
            kf[2 * t]     = s2h(*(const short8*)(kr + (lg ^ swz) * 8));
            kf[2 * t + 1] = s2h(*(const short8*)(kr + ((lg + 4) ^ swz) * 8));
        }

        // ---- QK + softmax per q-sub ----
        h8u pa[2][2];
#pragma unroll
        for (int s = 0; s < 2; ++s) {
            f32x4 sacc[4] = {};
            __builtin_amdgcn_s_setprio(1);
#pragma unroll
            for (int t = 0; t < 4; ++t) {
                sacc[t] = __builtin_amdgcn_mfma_f32_16x16x32_f16(kf[2 * t], qf[s][0], sacc[t], 0, 0, 0);
                sacc[t] = __builtin_amdgcn_mfma_f32_16x16x32_f16(kf[2 * t + 1], qf[s][1], sacc[t], 0, 0, 0);
            }
            __builtin_amdgcn_s_setprio(0);

            float tm0 = fmaxf(fmaxf(sacc[0][0], sacc[0][1]), fmaxf(sacc[0][2], sacc[0][3]));
            float tm1 = fmaxf(fmaxf(sacc[1][0], sacc[1][1]), fmaxf(sacc[1][2], sacc[1][3]));
            float tm2 = fmaxf(fmaxf(sacc[2][0], sacc[2][1]), fmaxf(sacc[2][2], sacc[2][3]));
            float tm3 = fmaxf(fmaxf(sacc[3][0], sacc[3][1]), fmaxf(sacc[3][2], sacc[3][3]));
            float tm = fmaxf(fmaxf(tm0, tm1), fmaxf(tm2, tm3));
            tm = fmaxf(tm, __shfl_xor(tm, 16));
            tm = fmaxf(tm, __shfl_xor(tm, 32));

            if (!__all(tm - mrow[s] <= RESC_THR)) {
                float nm = fmaxf(mrow[s], tm);
                float al = __builtin_amdgcn_exp2f(mrow[s] - nm);
                mrow[s] = nm;
                lsum[s] *= al;
#pragma unroll
                for (int r = 0; r < 4; ++r) {
                    float alq = __shfl(al, lg * 4 + r);
#pragma unroll
                    for (int dt = 0; dt < 4; ++dt) oacc[s][dt][r] *= alq;
                }
            }

            float ps = 0.f;
#pragma unroll
            for (int t = 0; t < 4; ++t) {
                float e0 = __builtin_amdgcn_exp2f(sacc[t][0] - mrow[s]);
                float e1 = __builtin_amdgcn_exp2f(sacc[t][1] - mrow[s]);
                float e2 = __builtin_amdgcn_exp2f(sacc[t][2] - mrow[s]);
                float e3 = __builtin_amdgcn_exp2f(sacc[t][3] - mrow[s]);
                ps += (e0 + e1) + (e2 + e3);
                pa[s][t >> 1].h2[(t & 1) * 2]     = __builtin_amdgcn_cvt_pkrtz(e0, e1);
                pa[s][t >> 1].h2[(t & 1) * 2 + 1] = __builtin_amdgcn_cvt_pkrtz(e2, e3);
            }
            ps += __shfl_xor(ps, 16);
            ps += __shfl_xor(ps, 32);
            lsum[s] += ps;
        }

        // ---- PV: 8 V b128 reads, each feeds both q-subs (16 mfma) ----
        __builtin_amdgcn_s_setprio(1);
#pragma unroll
        for (int m2 = 0; m2 < 2; ++m2)
#pragma unroll
            for (int dt = 0; dt < 4; ++dt) {
                int vcol = ((m2 * 4 + lg) ^ (lr & 7)) * 8;
                half8 vf = s2h(*(const short8*)&Vt[cur][dt * 16 + lr][vcol]);
                oacc[0][dt] = __builtin_amdgcn_mfma_f32_16x16x32_f16(pa[0][m2].h, vf, oacc[0][dt], 0, 0, 0);
                oacc[1][dt] = __builtin_amdgcn_mfma_f32_16x16x32_f16(pa[1][m2].h, vf, oacc[1][dt], 0, 0, 0);
            }
        __builtin_amdgcn_s_setprio(0);

        // ---- commit V(ti+1) ----
        if (ti + 1 < NT) {
#pragma unroll
            for (int j = 0; j < 4; ++j) {
                int d = d0 + j;
                short4v t4 = {ld[0][j], ld[1][j], ld[2][j], ld[3][j]};
                *(short4v*)&Vt[nxt][d][((kvpg ^ (d & 7)) << 3) + kvpo] = t4;
            }
        }
    }

    // ---- epilogue ----
    int b = bh >> 4, h = bh & 15;
#pragma unroll
    for (int s = 0; s < 2; ++s)
#pragma unroll
        for (int r = 0; r < 4; ++r) {
            float ls = __shfl(lsum[s], lg * 4 + r);
            float inv = 1.0f / ls;
            size_t orow = ((size_t)b * N_ + q0 + w * 32 + s * 16 + lg * 4 + r) * INNER_ + h * 64 + lr;
#pragma unroll
            for (int dt = 0; dt < 4; ++dt)
                Oh[orow + 16 * dt] = f2h(oacc[s][dt][r] * inv);
        }
}

// ---------------------------------------------------------------------------
extern "C" void kernel_launch(void* const* d_in, const int* in_sizes, int n_in,
                              void* d_out, int out_size, void* d_ws, size_t ws_size,
                              hipStream_t stream) {
    const float* x     = (const float*)d_in[0];
    const float* w_qkv = (const float*)d_in[1];
    const float* w_out = (const float*)d_in[2];
    const float* b_out = (const float*)d_in[3];
    float* out = (float*)d_out;

    unsigned short* Xh  = (unsigned short*)d_ws;     // 4M elems (reused as Oh)
    unsigned short* WqT = Xh + 4194304;              // 3M
    unsigned short* WoT = WqT + 3145728;             // 1M
    unsigned short* Qh  = WoT + 1048576;             // 4M
    unsigned short* Kh  = Qh + 4194304;              // 4M
    unsigned short* Vh  = Kh + 4194304;              // 4M

    convert_x<<<dim3(2048), 256, 0, stream>>>(x, Xh);
    convert_w_T<<<dim3(QKVC_ / 64, 16), 256, 0, stream>>>(w_qkv, WqT, QKVC_);
    convert_w_T<<<dim3(DIM_ / 64, 16), 256, 0, stream>>>(w_out, WoT, DIM_);

    qkv_gemm_mfma<<<dim3(QKVC_ / 128, 32), 256, 0, stream>>>(Xh, WqT, Qh, Kh, Vh);
    rope_kernel<<<dim3(2048), 256, 0, stream>>>(Qh, Kh);
    attn_mfma<<<dim3(N_ / 128, B_ * H_), 256, 0, stream>>>(Qh, Kh, Vh, Xh);
    out_gemm_mfma<<<dim3(DIM_ / 128, 32), 256, 0, stream>>>(Xh, WoT, b_out, out);
}